// Round 8
// baseline (1989.042 us; speedup 1.0000x reference)
//
#include <hip/hip_runtime.h>

#define DEV __device__ __forceinline__

typedef float f4_t __attribute__((ext_vector_type(4)));
typedef short v8s  __attribute__((ext_vector_type(8)));

DEV float lo16(unsigned int w){ return __uint_as_float(w << 16); }
DEV float hi16(unsigned int w){ return __uint_as_float(w & 0xffff0000u); }
DEV float b2f(unsigned short u){ return __uint_as_float((unsigned)u << 16); }
DEV unsigned short f2b(float f){
  unsigned int x = __float_as_uint(f);
  x += 0x7fffu + ((x >> 16) & 1u);     // round-to-nearest-even (finite values)
  return (unsigned short)(x >> 16);
}
DEV float geluf(float v){ return 0.5f * v * (1.0f + erff(v * 0.7071067811865475f)); }

DEV void gload_lds16(const unsigned short* g, unsigned short* l){
  __builtin_amdgcn_global_load_lds(
      (const __attribute__((address_space(1))) void*)g,
      (__attribute__((address_space(3))) void*)l, 16, 0, 0);
}

#define WAITV(n) asm volatile("s_waitcnt vmcnt(" #n ")" ::: "memory")
#define SBAR()  do{ __builtin_amdgcn_sched_barrier(0); \
                    asm volatile("s_barrier" ::: "memory"); \
                    __builtin_amdgcn_sched_barrier(0); }while(0)

// ---------------------------------------------------------------- prep ----
__global__ void k_prep(
    const float* Wq24, const float* Wk24, const float* Wv24,
    const float* Wq77, const float* Wk77, const float* Wv77,
    const float* Wqx,  const float* Wkx,  const float* Wvx,
    const float* bq24, const float* bk24, const float* bv24,
    const float* bq77, const float* bk77, const float* bv77,
    const float* bqx,  const float* bkx,  const float* bvx,
    const float* Wout, const float* W1,   const float* W2,
    const float* radar_w,
    unsigned short* wt_cat, unsigned short* wout_t,
    unsigned short* w1_t, unsigned short* w2_t,
    float* bias_cat, float* rwbuf, float* out_tail)
{
  long idx = (long)blockIdx.x * blockDim.x + threadIdx.x;
  if (idx < 589824){                       // Wt_cat[3][768][256] = W[k][n] -> [n][k] bf16
    int s = (int)(idx / 196608);
    int r = (int)(idx % 196608);
    int ng = r >> 8, k = r & 255;
    int which = ng >> 8, n = ng & 255;
    const float* src;
    switch (s*3 + which){
      case 0: src = Wq24; break;  case 1: src = Wk24; break;  case 2: src = Wv24; break;
      case 3: src = Wq77; break;  case 4: src = Wk77; break;  case 5: src = Wv77; break;
      case 6: src = Wqx;  break;  case 7: src = Wkx;  break;  default: src = Wvx; break;
    }
    wt_cat[idx] = f2b(src[k*256 + n]);
    return;
  }
  idx -= 589824;
  if (idx < 65536){ int n = (int)(idx >> 8), k = (int)(idx & 255);
    wout_t[idx] = f2b(Wout[k*256 + n]); return; }
  idx -= 65536;
  if (idx < 262144){ int n = (int)(idx >> 8), k = (int)(idx & 255);   // W1t[1024][256]
    w1_t[idx] = f2b(W1[k*1024 + n]); return; }
  idx -= 262144;
  if (idx < 262144){ int n = (int)(idx >> 10), k = (int)(idx & 1023); // W2t[256][1024]
    w2_t[idx] = f2b(W2[k*256 + n]); return; }
  idx -= 262144;
  if (idx < 2304){
    int s = (int)(idx / 768), j = (int)(idx % 768);
    int which = j >> 8, jj = j & 255;
    const float* src;
    switch (s*3 + which){
      case 0: src = bq24; break;  case 1: src = bk24; break;  case 2: src = bv24; break;
      case 3: src = bq77; break;  case 4: src = bk77; break;  case 5: src = bv77; break;
      case 6: src = bqx;  break;  case 7: src = bkx;  break;  default: src = bvx; break;
    }
    bias_cat[idx] = src[jj]; return;
  }
  idx -= 2304;
  if (idx < 3){
    float w0 = radar_w[0], w1v = radar_w[1], w2v = radar_w[2];
    float m = fmaxf(w0, fmaxf(w1v, w2v));
    float e0 = __expf(w0-m), e1 = __expf(w1v-m), e2 = __expf(w2v-m);
    float inv = 1.0f/(e0+e1+e2);
    float rw = (idx==0 ? e0 : (idx==1 ? e1 : e2)) * inv;
    rwbuf[idx] = rw; out_tail[idx] = rw;
  }
}

// --------------------------------------------------------------- 3x LN ----
__global__ __launch_bounds__(256) void k_ln3(
    const float* __restrict__ f24, const float* __restrict__ f77, const float* __restrict__ fx,
    const float* __restrict__ gg, const float* __restrict__ bb,
    unsigned short* __restrict__ nbuf, float* __restrict__ resid, int rows)
{
  int wid = threadIdx.x >> 6, lane = threadIdx.x & 63;
  long row = (long)blockIdx.x*4 + wid;
  long base = row*256 + lane*4;
  f4_t x0 = *(const f4_t*)(f24 + base);
  f4_t x1 = *(const f4_t*)(f77 + base);
  f4_t x2 = *(const f4_t*)(fx  + base);
  float s[3], q[3];
  s[0]=x0.x+x0.y+x0.z+x0.w;
  s[1]=x1.x+x1.y+x1.z+x1.w;
  s[2]=x2.x+x2.y+x2.z+x2.w;
  q[0]=fmaf(x0.x,x0.x,fmaf(x0.y,x0.y,fmaf(x0.z,x0.z,x0.w*x0.w)));
  q[1]=fmaf(x1.x,x1.x,fmaf(x1.y,x1.y,fmaf(x1.z,x1.z,x1.w*x1.w)));
  q[2]=fmaf(x2.x,x2.x,fmaf(x2.y,x2.y,fmaf(x2.z,x2.z,x2.w*x2.w)));
  #pragma unroll
  for (int m=1;m<64;m<<=1){
    #pragma unroll
    for (int j=0;j<3;j++){ s[j]+=__shfl_xor(s[j],m); q[j]+=__shfl_xor(q[j],m); }
  }
  f4_t G  = *(const f4_t*)(gg + lane*4);
  f4_t Bv = *(const f4_t*)(bb + lane*4);
  long strm = (long)rows*256;
  {
    float mean = s[0]*(1.0f/256.0f);
    float rstd = rsqrtf(q[0]*(1.0f/256.0f) - mean*mean + 1e-5f);
    ushort4 o;
    o.x=f2b((x0.x-mean)*rstd*G.x+Bv.x); o.y=f2b((x0.y-mean)*rstd*G.y+Bv.y);
    o.z=f2b((x0.z-mean)*rstd*G.z+Bv.z); o.w=f2b((x0.w-mean)*rstd*G.w+Bv.w);
    *(ushort4*)(nbuf + base) = o;
  }
  {
    float mean = s[1]*(1.0f/256.0f);
    float rstd = rsqrtf(q[1]*(1.0f/256.0f) - mean*mean + 1e-5f);
    ushort4 o;
    o.x=f2b((x1.x-mean)*rstd*G.x+Bv.x); o.y=f2b((x1.y-mean)*rstd*G.y+Bv.y);
    o.z=f2b((x1.z-mean)*rstd*G.z+Bv.z); o.w=f2b((x1.w-mean)*rstd*G.w+Bv.w);
    *(ushort4*)(nbuf + strm + base) = o;
  }
  {
    float mean = s[2]*(1.0f/256.0f);
    float rstd = rsqrtf(q[2]*(1.0f/256.0f) - mean*mean + 1e-5f);
    ushort4 o;
    o.x=f2b((x2.x-mean)*rstd*G.x+Bv.x); o.y=f2b((x2.y-mean)*rstd*G.y+Bv.y);
    o.z=f2b((x2.z-mean)*rstd*G.z+Bv.z); o.w=f2b((x2.w-mean)*rstd*G.w+Bv.w);
    *(ushort4*)(nbuf + 2*strm + base) = o;
  }
  f4_t rs;
  rs.x=(x0.x+x1.x+x2.x)*(1.0f/3.0f);
  rs.y=(x0.y+x1.y+x2.y)*(1.0f/3.0f);
  rs.z=(x0.z+x1.z+x2.z)*(1.0f/3.0f);
  rs.w=(x0.w+x1.w+x2.w)*(1.0f/3.0f);
  *(f4_t*)(resid + base) = rs;
}

// ------------------------------------------------- generic K=256 GEMM ----
// A[M][256] bf16 row-major, Bt[N][256] bf16 (= W^T). 128x128 tile, BK=64,
// ONE tile per block (epilogue at kernel end, off the vmcnt critical path;
// cross-tile pipelining via block churn, 2 blocks/CU). XOR-swizzled LDS
// (both-sides with global_load_lds); swapped MFMA operands -> lane owns
// (row, 4 consecutive cols) -> ushort4 epilogue.
// EPI: 0 = +bias -> bf16 ; 1 = +bias+resid -> bf16 ; 2 = gelu(+bias) -> bf16
template<int EPI>
__global__ __launch_bounds__(256,2) void k_gemm256(
    const unsigned short* __restrict__ A, const unsigned short* __restrict__ Bt,
    const float* __restrict__ bias, const float* __restrict__ resid,
    unsigned short* __restrict__ outH,
    long aBatch, long bBatch, long biasBatch, long oBatch, int ldOut)
{
  __shared__ __align__(16) unsigned short As[2][128][64];
  __shared__ __align__(16) unsigned short Bs[2][128][64];
  int tid = threadIdx.x, wid = tid >> 6, lane = tid & 63;
  int wm = (wid >> 1)*64, wn = (wid & 1)*64;
  int lr = lane & 15, lk = lane >> 4;
  long m0 = (long)blockIdx.x * 128;
  int  n0 = blockIdx.y * 128;
  int  z  = blockIdx.z;
  const unsigned short* Ab = A  + (long)z*aBatch + m0*256;
  const unsigned short* Bb = Bt + (long)z*bBatch + (long)n0*256;

  auto stage = [&](int s){
    int k0 = s*64, bi = s & 1;
    #pragma unroll
    for (int i=0;i<4;i++){
      int c = (wid*4+i)*64 + lane;
      int r = c >> 3, sl = (c & 7) ^ (r & 7);          // pre-swizzled source
      gload_lds16(Ab + (long)r*256 + k0 + sl*8, &As[bi][0][0] + (long)(wid*4+i)*512);
      gload_lds16(Bb + (long)r*256 + k0 + sl*8, &Bs[bi][0][0] + (long)(wid*4+i)*512);
    }
  };

  // preload bias (4 cols per fn, lane-owned) -- drained by first WAITV
  const float* bp = bias + (long)z*biasBatch;
  f4_t bv[4];
  #pragma unroll
  for (int fn=0; fn<4; fn++) bv[fn] = *(const f4_t*)(bp + n0 + wn + fn*16 + lk*4);

  f4_t acc[4][4] = {};
  stage(0);
  #pragma unroll
  for (int s=0; s<4; ++s){
    if (s < 3){ stage(s+1); WAITV(8); }    // drain buf[s] loads (+bias), keep next in flight
    else      { WAITV(0); }
    SBAR();
    int cur = s & 1;
    #pragma unroll
    for (int ks=0; ks<2; ++ks){
      v8s af[4], bfv[4];
      #pragma unroll
      for (int f=0; f<4; f++){
        int prA = wm + f*16 + lr;
        int prB = wn + f*16 + lr;
        int js  = ks*4 + lk;
        af[f]  = *(const v8s*)&As[cur][prA][(js ^ (prA & 7))*8];   // swizzled read
        bfv[f] = *(const v8s*)&Bs[cur][prB][(js ^ (prB & 7))*8];
      }
      #pragma unroll
      for (int fm=0; fm<4; fm++)
        #pragma unroll
        for (int fn=0; fn<4; fn++)
          acc[fm][fn] = __builtin_amdgcn_mfma_f32_16x16x32_bf16(bfv[fn], af[fm], acc[fm][fn], 0,0,0);
    }
    if (s < 3) SBAR();                     // protect buf[s] before stage(s+2) overwrite
  }

  // epilogue: fire-and-forget stores, off any pipeline critical path
  long zo = (long)z*oBatch;
  #pragma unroll
  for (int fm=0; fm<4; fm++){
    long gm = m0 + wm + fm*16 + lr;                    // lane owns this row
    long rowo = zo + gm*(long)ldOut;
    #pragma unroll
    for (int fn=0; fn<4; fn++){
      int gn = n0 + wn + fn*16 + lk*4;                 // 4 consecutive cols
      f4_t v = acc[fm][fn];
      v.x += bv[fn].x; v.y += bv[fn].y; v.z += bv[fn].z; v.w += bv[fn].w;
      if (EPI == 1){
        f4_t rv = *(const f4_t*)(resid + rowo + gn);
        v.x += rv.x; v.y += rv.y; v.z += rv.z; v.w += rv.w;
      }
      if (EPI == 2){ v.x=geluf(v.x); v.y=geluf(v.y); v.z=geluf(v.z); v.w=geluf(v.w); }
      ushort4 o; o.x=f2b(v.x); o.y=f2b(v.y); o.z=f2b(v.z); o.w=f2b(v.w);
      *(ushort4*)(outH + rowo + gn) = o;
    }
  }
}

// ---------------------------------------------------- per-row attention ----
// one wave per row, 4 rows / 256-thread block (23 KB LDS -> 6 blocks/CU).
// lane = h*8+g. LDS vectors padded to 40 ushorts (80B) for conflict-free b128.
__global__ __launch_bounds__(256,6) void k_attn(
    const unsigned short* __restrict__ qkv, const float* __restrict__ rwb,
    unsigned short* __restrict__ outA, int rows)
{
  __shared__ __align__(16) unsigned short L[4][72][40];
  int tid = threadIdx.x, wid = tid >> 6, lane = tid & 63;
  long brow0 = (long)blockIdx.x * 4;
  for (int c = tid; c < 1152; c += 256){
    int row = c / 288, rem = c % 288;
    int s = rem / 96, cc = rem % 96;
    int vi = cc >> 2, ch = cc & 3;
    const uint4* src = (const uint4*)(qkv + ((long)s*rows + brow0 + row)*768 + cc*8);
    *(uint4*)&L[row][s*24 + vi][ch*8] = *src;
  }
  __syncthreads();

  int h = lane >> 3, g = lane & 7;
  const unsigned short* R = &L[wid][0][0];
  float comb[32];
  #pragma unroll
  for (int i=0;i<32;i++) comb[i] = 0.0f;
  float rw0 = rwb[0], rw1 = rwb[1], rw2 = rwb[2];

  #pragma unroll
  for (int att=0; att<3; ++att){
    int qs  = att;
    int as_ = (att==0) ? 1 : 0;
    int bs_ = (att==2) ? 1 : 2;
    float rwv = (att==0) ? rw0 : ((att==1) ? rw1 : rw2);
    const unsigned short* qp  = R + (qs *24      + h)*40;
    const unsigned short* kap = R + (as_*24 + 8  + g)*40;
    const unsigned short* kbp = R + (bs_*24 + 8  + g)*40;
    float a = 0.0f, b = 0.0f;
    #pragma unroll
    for (int j=0;j<4;j++){
      uint4 qc  = *(const uint4*)(qp  + j*8);
      uint4 kac = *(const uint4*)(kap + j*8);
      uint4 kbc = *(const uint4*)(kbp + j*8);
      #define DOT2(QW,KA,KB) { float q0=lo16(QW), q1=hi16(QW); \
        a=fmaf(q0,lo16(KA),a); a=fmaf(q1,hi16(KA),a); \
        b=fmaf(q0,lo16(KB),b); b=fmaf(q1,hi16(KB),b); }
      DOT2(qc.x, kac.x, kbc.x) DOT2(qc.y, kac.y, kbc.y)
      DOT2(qc.z, kac.z, kbc.z) DOT2(qc.w, kac.w, kbc.w)
      #undef DOT2
    }
    float d  = (b - a) * 0.17677669529663689f;
    float p0 = 1.0f / (1.0f + __expf(d));
    float p1 = 1.0f - p0;
    float w0 = rwv * p0, w1 = rwv * p1;
    const unsigned short* vap = R + (as_*24 + 16 + g)*40;
    const unsigned short* vbp = R + (bs_*24 + 16 + g)*40;
    #pragma unroll
    for (int j=0;j<4;j++){
      uint4 va = *(const uint4*)(vap + j*8);
      uint4 vb = *(const uint4*)(vbp + j*8);
      #define MIX2(VA,VB,C0,C1) { \
        C0 = fmaf(w0, lo16(VA), fmaf(w1, lo16(VB), C0)); \
        C1 = fmaf(w0, hi16(VA), fmaf(w1, hi16(VB), C1)); }
      MIX2(va.x, vb.x, comb[j*8+0], comb[j*8+1])
      MIX2(va.y, vb.y, comb[j*8+2], comb[j*8+3])
      MIX2(va.z, vb.z, comb[j*8+4], comb[j*8+5])
      MIX2(va.w, vb.w, comb[j*8+6], comb[j*8+7])
      #undef MIX2
    }
  }

  // reduce-scatter over g (xor 4,2,1): lane (h,g) ends with d = g*4..g*4+3
  float t16[16];
  { bool up = (lane & 4) != 0;
    #pragma unroll
    for (int i=0;i<16;i++){
      float send = up ? comb[i] : comb[16+i];
      float keep = up ? comb[16+i] : comb[i];
      t16[i] = keep + __shfl_xor(send, 4);
    } }
  float t8[8];
  { bool up = (lane & 2) != 0;
    #pragma unroll
    for (int i=0;i<8;i++){
      float send = up ? t16[i] : t16[8+i];
      float keep = up ? t16[8+i] : t16[i];
      t8[i] = keep + __shfl_xor(send, 2);
    } }
  float t4[4];
  { bool up = (lane & 1) != 0;
    #pragma unroll
    for (int i=0;i<4;i++){
      float send = up ? t8[i] : t8[4+i];
      float keep = up ? t8[4+i] : t8[i];
      t4[i] = keep + __shfl_xor(send, 1);
    } }

  long orow = brow0 + wid;
  ushort4 o4;
  o4.x = f2b(t4[0]); o4.y = f2b(t4[1]); o4.z = f2b(t4[2]); o4.w = f2b(t4[3]);
  *(ushort4*)(outA + orow*256 + lane*4) = o4;
}

// ------------------------------------- FF2 (K=1024) + bias + add + LN ----
// BM=64, BN=256 (block owns whole rows), 8 waves (2m x 4n), wave 32x64.
__global__ __launch_bounds__(512,4) void k_ff2ln(
    const unsigned short* __restrict__ A, const unsigned short* __restrict__ Bt,
    const float* __restrict__ b2, const unsigned short* __restrict__ fusedH,
    const float* __restrict__ fg, const float* __restrict__ fb,
    float* __restrict__ dout)
{
  __shared__ __align__(16) union {
    struct { unsigned short As[2][64][64]; unsigned short Bs[2][256][64]; } st;
    float rowbuf[64][264];
  } u;
  int tid = threadIdx.x, wid = tid >> 6, lane = tid & 63;
  long m0 = (long)blockIdx.x * 64;
  const unsigned short* Ab = A + m0*1024;

  auto stage = [&](int it){
    int k0 = (it)*64, bi = it & 1;
    { int c = wid*64 + lane; int r = c >> 3, sl = (c & 7) ^ (r & 7);
      gload_lds16(Ab + (long)r*1024 + k0 + sl*8, &u.st.As[bi][0][0] + (long)wid*512); }
    #pragma unroll
    for (int i=0;i<4;i++){
      int j = wid*4 + i; int c = j*64 + lane; int r = c >> 3, sl = (c & 7) ^ (r & 7);
      gload_lds16(Bt + (long)r*1024 + k0 + sl*8, &u.st.Bs[bi][0][0] + (long)j*512);
    }
  };

  f4_t acc[2][4] = {};
  int wm = (wid >> 2)*32, wn = (wid & 3)*64;
  int lr = lane & 15, lk = lane >> 4;

  stage(0);
  for (int it=0; it<16; ++it){
    if (it+1 < 16){ stage(it+1); WAITV(5); }
    else          { WAITV(0); }
    SBAR();
    int cur = it & 1;
    #pragma unroll
    for (int ks=0; ks<2; ++ks){
      v8s af[2], bfv[4];
      #pragma unroll
      for (int f=0; f<2; f++){
        int pr = wm + f*16 + lr;
        af[f]  = *(const v8s*)&u.st.As[cur][pr][((ks*4+lk) ^ (pr & 7))*8];
      }
      #pragma unroll
      for (int f=0; f<4; f++){
        int pr = wn + f*16 + lr;
        bfv[f] = *(const v8s*)&u.st.Bs[cur][pr][((ks*4+lk) ^ (pr & 7))*8];
      }
      #pragma unroll
      for (int fm=0; fm<2; fm++)
        #pragma unroll
        for (int fn=0; fn<4; fn++)
          acc[fm][fn] = __builtin_amdgcn_mfma_f32_16x16x32_bf16(bfv[fn], af[fm], acc[fm][fn], 0,0,0);
    }
    SBAR();
  }

  // all waves past final barrier -> safe to reuse LDS as rowbuf
  #pragma unroll
  for (int fm=0; fm<2; fm++){
    int rl = wm + fm*16 + lr;                    // lane owns this row
    #pragma unroll
    for (int fn=0; fn<4; fn++){
      int cl = wn + fn*16 + lk*4;                // 4 consecutive cols
      f4_t bv = *(const f4_t*)(b2 + cl);
      ushort4 fh = *(const ushort4*)(fusedH + (m0 + rl)*256 + cl);
      f4_t v = acc[fm][fn];
      v.x += bv.x + b2f(fh.x);
      v.y += bv.y + b2f(fh.y);
      v.z += bv.z + b2f(fh.z);
      v.w += bv.w + b2f(fh.w);
      *(f4_t*)&u.rowbuf[rl][cl] = v;
    }
  }
  __syncthreads();

  f4_t G  = *(const f4_t*)(fg + lane*4);
  f4_t Bv = *(const f4_t*)(fb + lane*4);
  #pragma unroll
  for (int rr=0; rr<8; ++rr){
    int row = wid*8 + rr;
    f4_t x = *(const f4_t*)&u.rowbuf[row][lane*4];
    float s = x.x + x.y + x.z + x.w;
    float q = fmaf(x.x,x.x, fmaf(x.y,x.y, fmaf(x.z,x.z, x.w*x.w)));
    #pragma unroll
    for (int m=1;m<64;m<<=1){ s += __shfl_xor(s,m); q += __shfl_xor(q,m); }
    float mean = s*(1.0f/256.0f);
    float rstd = rsqrtf(q*(1.0f/256.0f) - mean*mean + 1e-5f);
    f4_t o;
    o.x = (x.x-mean)*rstd*G.x + Bv.x;
    o.y = (x.y-mean)*rstd*G.y + Bv.y;
    o.z = (x.z-mean)*rstd*G.z + Bv.z;
    o.w = (x.w-mean)*rstd*G.w + Bv.w;
    *(f4_t*)(dout + (m0 + row)*256 + lane*4) = o;
  }
}

// ---------------------------------------------------------------- host ----
extern "C" void kernel_launch(void* const* d_in, const int* in_sizes, int n_in,
                              void* d_out, int out_size, void* d_ws, size_t ws_size,
                              hipStream_t stream)
{
  const float* f24    = (const float*)d_in[0];
  const float* f77    = (const float*)d_in[1];
  const float* fx     = (const float*)d_in[2];
  const float* norm_g = (const float*)d_in[3];
  const float* norm_b = (const float*)d_in[4];
  const float* Wq24 = (const float*)d_in[5];  const float* bq24 = (const float*)d_in[6];
  const float* Wk24 = (const float*)d_in[7];  const float* bk24 = (const float*)d_in[8];
  const float* Wv24 = (const float*)d_in[9];  const float* bv24 = (const float*)d_in[10];
  const float* Wq77 = (const float*)d_in[11]; const float* bq77 = (const float*)d_in[12];
  const float* Wk77 = (const float*)d_in[13]; const float* bk77 = (const float*)d_in[14];
  const float* Wv77 = (const float*)d_in[15]; const float* bv77 = (const float*)d_in[16];
  const float* Wqx  = (const float*)d_in[17]; const float* bqx  = (const float*)d_in[18];
  const float* Wkx  = (const float*)d_in[19]; const float* bkx  = (const float*)d_in[20];
  const float* Wvx  = (const float*)d_in[21]; const float* bvx  = (const float*)d_in[22];
  const float* Wout = (const float*)d_in[23]; const float* bout = (const float*)d_in[24];
  const float* radar_w = (const float*)d_in[25];
  const float* W1 = (const float*)d_in[26];   const float* b1 = (const float*)d_in[27];
  const float* W2 = (const float*)d_in[28];   const float* b2 = (const float*)d_in[29];
  const float* fnorm_g = (const float*)d_in[30];
  const float* fnorm_b = (const float*)d_in[31];

  const long Brows = (long)in_sizes[0] / 256;   // 131072
  float* dout = (float*)d_out;
  char* ws = (char*)d_ws;

  // ---- fixed (weights) region ----
  size_t off = 0;
  auto A_ = [&](size_t b){ size_t o = off; off = (off + b + 255) & ~(size_t)255; return o; };
  size_t oWT = A_((size_t)3*768*256*2);
  size_t oWO = A_((size_t)65536*2);
  size_t oW1 = A_((size_t)262144*2);
  size_t oW2 = A_((size_t)262144*2);
  size_t oBC = A_((size_t)2304*4);
  size_t oRW = A_(256);
  size_t fixedEnd = off;

  unsigned short* WT_CAT = (unsigned short*)(ws + oWT);
  unsigned short* WOUT_T = (unsigned short*)(ws + oWO);
  unsigned short* W1_T   = (unsigned short*)(ws + oW1);
  unsigned short* W2_T   = (unsigned short*)(ws + oW2);
  float*          BIASC  = (float*)(ws + oBC);
  float*          RW     = (float*)(ws + oRW);

  // ---- adaptive chunking over rows ----
  // per-row bytes: NBUF 3*256*2=1536 | RESID 256*4=1024 | QKV 3*768*2=4608
  const size_t PER_ROW = 7168;
  if (ws_size <= fixedEnd + 512) return;
  long maxR = (long)((ws_size - fixedEnd - 256) / PER_ROW);
  maxR &= ~127L;
  if (maxR < 128) return;
  long Rc = maxR < 16384 ? maxR : 16384;   // keep chunk working set ~L3-sized
  if (Rc > Brows) Rc = Brows;
  long nch = (Brows + Rc - 1) / Rc;
  Rc = ((Brows + nch - 1) / nch + 127) & ~127L;

  size_t chunkBase = (fixedEnd + 255) & ~(size_t)255;
  char* NB_B = ws + chunkBase;                              // 1536*Rc
  char* RS_B = NB_B + (size_t)1536*Rc;                      // 1024*Rc
  char* QK_B = RS_B + (size_t)1024*Rc;                      // 4608*Rc

  { // prep: weight transposes + bias concat + rw (also writes d_out tail)
    long total = 589824 + 65536 + 262144 + 262144 + 2304 + 3;
    int blocks = (int)((total + 255) / 256);
    k_prep<<<blocks, 256, 0, stream>>>(
        Wq24, Wk24, Wv24, Wq77, Wk77, Wv77, Wqx, Wkx, Wvx,
        bq24, bk24, bv24, bq77, bk77, bv77, bqx, bkx, bvx,
        Wout, W1, W2, radar_w,
        WT_CAT, WOUT_T, W1_T, W2_T, BIASC, RW, dout + (size_t)Brows*256);
  }

  for (long row0 = 0; row0 < Brows; row0 += Rc){
    long rows = Brows - row0 < Rc ? Brows - row0 : Rc;   // multiple of 128
    unsigned short* NBUF   = (unsigned short*)NB_B;
    float*          RESID  = (float*)RS_B;
    unsigned short* QKV    = (unsigned short*)QK_B;
    // aliases (lifetimes do not overlap within a chunk):
    unsigned short* ATTN   = (unsigned short*)NB_B;                        // rows*256 bf16
    unsigned short* FUSEDH = (unsigned short*)QK_B;                        // rows*256 bf16
    unsigned short* HBUF   = (unsigned short*)(QK_B + (size_t)rows*256*2); // rows*1024 bf16

    int tM = (int)(rows/128);

    k_ln3<<<(int)(rows/4), 256, 0, stream>>>(
        f24 + row0*256, f77 + row0*256, fx + row0*256,
        norm_g, norm_b, NBUF, RESID, (int)rows);

    k_gemm256<0><<<dim3(tM, 6, 3), 256, 0, stream>>>(
        NBUF, WT_CAT, BIASC, nullptr, QKV,
        rows*256L, 768L*256, 768L, rows*768L, 768);

    k_attn<<<(int)(rows/4), 256, 0, stream>>>(QKV, RW, ATTN, (int)rows);

    k_gemm256<1><<<dim3(tM, 2, 1), 256, 0, stream>>>(
        ATTN, WOUT_T, bout, RESID, FUSEDH,
        0, 0, 0, 0, 256);

    k_gemm256<2><<<dim3(tM, 8, 1), 256, 0, stream>>>(
        FUSEDH, W1_T, b1, nullptr, HBUF,
        0, 0, 0, 0, 1024);

    k_ff2ln<<<(int)(rows/64), 512, 0, stream>>>(
        HBUF, W2_T, b2, FUSEDH, fnorm_g, fnorm_b, dout + row0*256);
  }
}

// Round 9
// 1613.211 us; speedup vs baseline: 1.2330x; 1.2330x over previous
//
#include <hip/hip_runtime.h>

#define DEV __device__ __forceinline__

typedef float f4_t __attribute__((ext_vector_type(4)));
typedef short v8s  __attribute__((ext_vector_type(8)));

DEV float lo16(unsigned int w){ return __uint_as_float(w << 16); }
DEV float hi16(unsigned int w){ return __uint_as_float(w & 0xffff0000u); }
DEV float b2f(unsigned short u){ return __uint_as_float((unsigned)u << 16); }
DEV unsigned short f2b(float f){
  unsigned int x = __float_as_uint(f);
  x += 0x7fffu + ((x >> 16) & 1u);     // round-to-nearest-even (finite values)
  return (unsigned short)(x >> 16);
}
DEV float geluf(float v){ return 0.5f * v * (1.0f + erff(v * 0.7071067811865475f)); }

DEV void gload_lds16(const unsigned short* g, unsigned short* l){
  __builtin_amdgcn_global_load_lds(
      (const __attribute__((address_space(1))) void*)g,
      (__attribute__((address_space(3))) void*)l, 16, 0, 0);
}

#define WAITV(n) asm volatile("s_waitcnt vmcnt(" #n ")" ::: "memory")
#define SBAR()  do{ __builtin_amdgcn_sched_barrier(0); \
                    asm volatile("s_barrier" ::: "memory"); \
                    __builtin_amdgcn_sched_barrier(0); }while(0)

// ---------------------------------------------------------------- prep ----
__global__ void k_prep(
    const float* Wq24, const float* Wk24, const float* Wv24,
    const float* Wq77, const float* Wk77, const float* Wv77,
    const float* Wqx,  const float* Wkx,  const float* Wvx,
    const float* bq24, const float* bk24, const float* bv24,
    const float* bq77, const float* bk77, const float* bv77,
    const float* bqx,  const float* bkx,  const float* bvx,
    const float* Wout, const float* W1,   const float* W2,
    const float* radar_w,
    unsigned short* wt_cat, unsigned short* wout_t,
    unsigned short* w1_t, unsigned short* w2_t,
    float* bias_cat, float* rwbuf, float* out_tail)
{
  long idx = (long)blockIdx.x * blockDim.x + threadIdx.x;
  if (idx < 589824){                       // Wt_cat[3][768][256] = W[k][n] -> [n][k] bf16
    int s = (int)(idx / 196608);
    int r = (int)(idx % 196608);
    int ng = r >> 8, k = r & 255;
    int which = ng >> 8, n = ng & 255;
    const float* src;
    switch (s*3 + which){
      case 0: src = Wq24; break;  case 1: src = Wk24; break;  case 2: src = Wv24; break;
      case 3: src = Wq77; break;  case 4: src = Wk77; break;  case 5: src = Wv77; break;
      case 6: src = Wqx;  break;  case 7: src = Wkx;  break;  default: src = Wvx; break;
    }
    wt_cat[idx] = f2b(src[k*256 + n]);
    return;
  }
  idx -= 589824;
  if (idx < 65536){ int n = (int)(idx >> 8), k = (int)(idx & 255);
    wout_t[idx] = f2b(Wout[k*256 + n]); return; }
  idx -= 65536;
  if (idx < 262144){ int n = (int)(idx >> 8), k = (int)(idx & 255);   // W1t[1024][256]
    w1_t[idx] = f2b(W1[k*1024 + n]); return; }
  idx -= 262144;
  if (idx < 262144){ int n = (int)(idx >> 10), k = (int)(idx & 1023); // W2t[256][1024]
    w2_t[idx] = f2b(W2[k*256 + n]); return; }
  idx -= 262144;
  if (idx < 2304){
    int s = (int)(idx / 768), j = (int)(idx % 768);
    int which = j >> 8, jj = j & 255;
    const float* src;
    switch (s*3 + which){
      case 0: src = bq24; break;  case 1: src = bk24; break;  case 2: src = bv24; break;
      case 3: src = bq77; break;  case 4: src = bk77; break;  case 5: src = bv77; break;
      case 6: src = bqx;  break;  case 7: src = bkx;  break;  default: src = bvx; break;
    }
    bias_cat[idx] = src[jj]; return;
  }
  idx -= 2304;
  if (idx < 3){
    float w0 = radar_w[0], w1v = radar_w[1], w2v = radar_w[2];
    float m = fmaxf(w0, fmaxf(w1v, w2v));
    float e0 = __expf(w0-m), e1 = __expf(w1v-m), e2 = __expf(w2v-m);
    float inv = 1.0f/(e0+e1+e2);
    float rw = (idx==0 ? e0 : (idx==1 ? e1 : e2)) * inv;
    rwbuf[idx] = rw; out_tail[idx] = rw;
  }
}

// --------------------------------------------------------------- 3x LN ----
__global__ __launch_bounds__(256) void k_ln3(
    const float* __restrict__ f24, const float* __restrict__ f77, const float* __restrict__ fx,
    const float* __restrict__ gg, const float* __restrict__ bb,
    unsigned short* __restrict__ nbuf, float* __restrict__ resid, int rows)
{
  int wid = threadIdx.x >> 6, lane = threadIdx.x & 63;
  long row = (long)blockIdx.x*4 + wid;
  long base = row*256 + lane*4;
  f4_t x0 = *(const f4_t*)(f24 + base);
  f4_t x1 = *(const f4_t*)(f77 + base);
  f4_t x2 = *(const f4_t*)(fx  + base);
  float s[3], q[3];
  s[0]=x0.x+x0.y+x0.z+x0.w;
  s[1]=x1.x+x1.y+x1.z+x1.w;
  s[2]=x2.x+x2.y+x2.z+x2.w;
  q[0]=fmaf(x0.x,x0.x,fmaf(x0.y,x0.y,fmaf(x0.z,x0.z,x0.w*x0.w)));
  q[1]=fmaf(x1.x,x1.x,fmaf(x1.y,x1.y,fmaf(x1.z,x1.z,x1.w*x1.w)));
  q[2]=fmaf(x2.x,x2.x,fmaf(x2.y,x2.y,fmaf(x2.z,x2.z,x2.w*x2.w)));
  #pragma unroll
  for (int m=1;m<64;m<<=1){
    #pragma unroll
    for (int j=0;j<3;j++){ s[j]+=__shfl_xor(s[j],m); q[j]+=__shfl_xor(q[j],m); }
  }
  f4_t G  = *(const f4_t*)(gg + lane*4);
  f4_t Bv = *(const f4_t*)(bb + lane*4);
  long strm = (long)rows*256;
  {
    float mean = s[0]*(1.0f/256.0f);
    float rstd = rsqrtf(q[0]*(1.0f/256.0f) - mean*mean + 1e-5f);
    ushort4 o;
    o.x=f2b((x0.x-mean)*rstd*G.x+Bv.x); o.y=f2b((x0.y-mean)*rstd*G.y+Bv.y);
    o.z=f2b((x0.z-mean)*rstd*G.z+Bv.z); o.w=f2b((x0.w-mean)*rstd*G.w+Bv.w);
    *(ushort4*)(nbuf + base) = o;
  }
  {
    float mean = s[1]*(1.0f/256.0f);
    float rstd = rsqrtf(q[1]*(1.0f/256.0f) - mean*mean + 1e-5f);
    ushort4 o;
    o.x=f2b((x1.x-mean)*rstd*G.x+Bv.x); o.y=f2b((x1.y-mean)*rstd*G.y+Bv.y);
    o.z=f2b((x1.z-mean)*rstd*G.z+Bv.z); o.w=f2b((x1.w-mean)*rstd*G.w+Bv.w);
    *(ushort4*)(nbuf + strm + base) = o;
  }
  {
    float mean = s[2]*(1.0f/256.0f);
    float rstd = rsqrtf(q[2]*(1.0f/256.0f) - mean*mean + 1e-5f);
    ushort4 o;
    o.x=f2b((x2.x-mean)*rstd*G.x+Bv.x); o.y=f2b((x2.y-mean)*rstd*G.y+Bv.y);
    o.z=f2b((x2.z-mean)*rstd*G.z+Bv.z); o.w=f2b((x2.w-mean)*rstd*G.w+Bv.w);
    *(ushort4*)(nbuf + 2*strm + base) = o;
  }
  f4_t rs;
  rs.x=(x0.x+x1.x+x2.x)*(1.0f/3.0f);
  rs.y=(x0.y+x1.y+x2.y)*(1.0f/3.0f);
  rs.z=(x0.z+x1.z+x2.z)*(1.0f/3.0f);
  rs.w=(x0.w+x1.w+x2.w)*(1.0f/3.0f);
  *(f4_t*)(resid + base) = rs;
}

// ------------------------------------------------- QKV GEMM (R7 form) ----
// A[M][256] bf16 row-major, Bt[N][256] bf16 (= W^T). 128x128 tile, BK=64.
// Grid-stride over tiles; counted vmcnt(8); XOR-swizzled LDS; swapped MFMA
// operands -> lane owns (row, 4 consecutive cols) -> ushort4 epilogue.
template<int EPI>
__global__ __launch_bounds__(256,2) void k_gemm256(
    const unsigned short* __restrict__ A, const unsigned short* __restrict__ Bt,
    const float* __restrict__ bias,
    unsigned short* __restrict__ outH,
    long aBatch, long bBatch, long biasBatch, long oBatch, int ldOut,
    int tM, int tN, int tZ)
{
  __shared__ __align__(16) unsigned short As[2][128][64];
  __shared__ __align__(16) unsigned short Bs[2][128][64];
  int tid = threadIdx.x, wid = tid >> 6, lane = tid & 63;
  int wm = (wid >> 1)*64, wn = (wid & 1)*64;
  int lr = lane & 15, lk = lane >> 4;

  int total = tM*tN*tZ;
  int nT = (total - (int)blockIdx.x + (int)gridDim.x - 1) / (int)gridDim.x;
  if (nT <= 0) return;
  int G = nT*4;

  auto tileOf = [&](int j, long& m0, int& n0, int& z){
    int T = (int)blockIdx.x + j*(int)gridDim.x;
    int mt = T % tM; int rest = T / tM;
    int nt = rest % tN; z = rest / tN;
    m0 = (long)mt*128; n0 = nt*128;
  };

  auto stage = [&](int g){
    long m0; int n0, z;
    tileOf(g >> 2, m0, n0, z);
    int k0 = (g & 3)*64, bi = g & 1;
    const unsigned short* Ab = A  + (long)z*aBatch + m0*256;
    const unsigned short* Bb = Bt + (long)z*bBatch + (long)n0*256;
    #pragma unroll
    for (int i=0;i<4;i++){
      int c = (wid*4+i)*64 + lane;
      int r = c >> 3, sl = (c & 7) ^ (r & 7);          // pre-swizzled source
      gload_lds16(Ab + (long)r*256 + k0 + sl*8, &As[bi][0][0] + (long)(wid*4+i)*512);
      gload_lds16(Bb + (long)r*256 + k0 + sl*8, &Bs[bi][0][0] + (long)(wid*4+i)*512);
    }
  };

  const f4_t fz = {0.f,0.f,0.f,0.f};
  f4_t acc[4][4] = {};

  stage(0);
  for (int g=0; g<G; ++g){
    if (g+1 < G){ stage(g+1); WAITV(8); }
    else        { WAITV(0); }
    SBAR();
    int cur = g & 1;
    #pragma unroll
    for (int ks=0; ks<2; ++ks){
      v8s af[4], bfv[4];
      #pragma unroll
      for (int f=0; f<4; f++){
        int prA = wm + f*16 + lr;
        int prB = wn + f*16 + lr;
        int js  = ks*4 + lk;
        af[f]  = *(const v8s*)&As[cur][prA][(js ^ (prA & 7))*8];   // swizzled read
        bfv[f] = *(const v8s*)&Bs[cur][prB][(js ^ (prB & 7))*8];
      }
      #pragma unroll
      for (int fm=0; fm<4; fm++)
        #pragma unroll
        for (int fn=0; fn<4; fn++)
          acc[fm][fn] = __builtin_amdgcn_mfma_f32_16x16x32_bf16(bfv[fn], af[fm], acc[fm][fn], 0,0,0);
    }
    if ((g & 3) == 3){
      long m0; int n0, z;
      tileOf(g >> 2, m0, n0, z);
      long zo = (long)z*oBatch;
      const float* bp = bias + (long)z*biasBatch;
      #pragma unroll
      for (int fm=0; fm<4; fm++){
        long gm = m0 + wm + fm*16 + lr;                 // lane owns this row
        long rowo = zo + gm*(long)ldOut;
        #pragma unroll
        for (int fn=0; fn<4; fn++){
          int gn = n0 + wn + fn*16 + lk*4;              // 4 consecutive cols
          f4_t bv = *(const f4_t*)(bp + gn);
          f4_t v = acc[fm][fn];
          v.x += bv.x; v.y += bv.y; v.z += bv.z; v.w += bv.w;
          ushort4 o; o.x=f2b(v.x); o.y=f2b(v.y); o.z=f2b(v.z); o.w=f2b(v.w);
          *(ushort4*)(outH + rowo + gn) = o;
          acc[fm][fn] = fz;                             // reset for next tile
        }
      }
    }
    SBAR();
  }
}

// ---------------------------------------------------- per-row attention ----
// R7 config: one wave per row, 8 rows / 512-thread block; 80B-padded vectors.
__global__ __launch_bounds__(512,4) void k_attn(
    const unsigned short* __restrict__ qkv, const float* __restrict__ rwb,
    unsigned short* __restrict__ outA, int rows)
{
  __shared__ __align__(16) unsigned short L[8][72][40];
  int tid = threadIdx.x, wid = tid >> 6, lane = tid & 63;
  long brow0 = (long)blockIdx.x * 8;
  for (int c = tid; c < 2304; c += 512){
    int row = c / 288, rem = c % 288;
    int s = rem / 96, cc = rem % 96;
    int vi = cc >> 2, ch = cc & 3;
    const uint4* src = (const uint4*)(qkv + ((long)s*rows + brow0 + row)*768 + cc*8);
    *(uint4*)&L[row][s*24 + vi][ch*8] = *src;
  }
  __syncthreads();

  int h = lane >> 3, g = lane & 7;
  const unsigned short* R = &L[wid][0][0];
  float comb[32];
  #pragma unroll
  for (int i=0;i<32;i++) comb[i] = 0.0f;
  float rw0 = rwb[0], rw1 = rwb[1], rw2 = rwb[2];

  #pragma unroll
  for (int att=0; att<3; ++att){
    int qs  = att;
    int as_ = (att==0) ? 1 : 0;
    int bs_ = (att==2) ? 1 : 2;
    float rwv = (att==0) ? rw0 : ((att==1) ? rw1 : rw2);
    const unsigned short* qp  = R + (qs *24      + h)*40;
    const unsigned short* kap = R + (as_*24 + 8  + g)*40;
    const unsigned short* kbp = R + (bs_*24 + 8  + g)*40;
    float a = 0.0f, b = 0.0f;
    #pragma unroll
    for (int j=0;j<4;j++){
      uint4 qc  = *(const uint4*)(qp  + j*8);
      uint4 kac = *(const uint4*)(kap + j*8);
      uint4 kbc = *(const uint4*)(kbp + j*8);
      #define DOT2(QW,KA,KB) { float q0=lo16(QW), q1=hi16(QW); \
        a=fmaf(q0,lo16(KA),a); a=fmaf(q1,hi16(KA),a); \
        b=fmaf(q0,lo16(KB),b); b=fmaf(q1,hi16(KB),b); }
      DOT2(qc.x, kac.x, kbc.x) DOT2(qc.y, kac.y, kbc.y)
      DOT2(qc.z, kac.z, kbc.z) DOT2(qc.w, kac.w, kbc.w)
      #undef DOT2
    }
    float d  = (b - a) * 0.17677669529663689f;
    float p0 = 1.0f / (1.0f + __expf(d));
    float p1 = 1.0f - p0;
    float w0 = rwv * p0, w1 = rwv * p1;
    const unsigned short* vap = R + (as_*24 + 16 + g)*40;
    const unsigned short* vbp = R + (bs_*24 + 16 + g)*40;
    #pragma unroll
    for (int j=0;j<4;j++){
      uint4 va = *(const uint4*)(vap + j*8);
      uint4 vb = *(const uint4*)(vbp + j*8);
      #define MIX2(VA,VB,C0,C1) { \
        C0 = fmaf(w0, lo16(VA), fmaf(w1, lo16(VB), C0)); \
        C1 = fmaf(w0, hi16(VA), fmaf(w1, hi16(VB), C1)); }
      MIX2(va.x, vb.x, comb[j*8+0], comb[j*8+1])
      MIX2(va.y, vb.y, comb[j*8+2], comb[j*8+3])
      MIX2(va.z, vb.z, comb[j*8+4], comb[j*8+5])
      MIX2(va.w, vb.w, comb[j*8+6], comb[j*8+7])
      #undef MIX2
    }
  }

  float t16[16];
  { bool up = (lane & 4) != 0;
    #pragma unroll
    for (int i=0;i<16;i++){
      float send = up ? comb[i] : comb[16+i];
      float keep = up ? comb[16+i] : comb[i];
      t16[i] = keep + __shfl_xor(send, 4);
    } }
  float t8[8];
  { bool up = (lane & 2) != 0;
    #pragma unroll
    for (int i=0;i<8;i++){
      float send = up ? t16[i] : t16[8+i];
      float keep = up ? t16[8+i] : t16[i];
      t8[i] = keep + __shfl_xor(send, 2);
    } }
  float t4[4];
  { bool up = (lane & 1) != 0;
    #pragma unroll
    for (int i=0;i<4;i++){
      float send = up ? t8[i] : t8[4+i];
      float keep = up ? t8[4+i] : t8[i];
      t4[i] = keep + __shfl_xor(send, 1);
    } }

  long orow = brow0 + wid;
  ushort4 o4;
  o4.x = f2b(t4[0]); o4.y = f2b(t4[1]); o4.z = f2b(t4[2]); o4.w = f2b(t4[3]);
  *(ushort4*)(outA + orow*256 + lane*4) = o4;
}

// ------------------- fused backend: Wout+resid -> FF1+gelu -> FF2 -> LN ----
// BM=32 rows/block, 256 threads (4 waves), 72KB LDS -> 2 blocks/CU.
// fused kept as bf16 in LDS (FL); H slices ping through R2; acc2 in regs.
__global__ __launch_bounds__(256,2) void k_back(
    const unsigned short* __restrict__ attn,  // chunk [rows][256] bf16
    const float* __restrict__ resid,          // chunk [rows][256] f32
    const unsigned short* __restrict__ woutT, // [256][256]
    const unsigned short* __restrict__ w1T,   // [1024][256]
    const unsigned short* __restrict__ w2T,   // [256][1024]
    const float* __restrict__ bout, const float* __restrict__ b1,
    const float* __restrict__ b2,
    const float* __restrict__ fg, const float* __restrict__ fb,
    float* __restrict__ dout)                 // chunk [rows][256] f32
{
  __shared__ __align__(16) unsigned short FL[8192];    // fused bf16 [32][256] swz
  __shared__ __align__(16) unsigned short STG[16384];  // B staging [<=256][64] swz
  __shared__ __align__(16) unsigned short R2[4096];    // As / HLDS[32][128] / partials
  int tid = threadIdx.x, wid = tid >> 6, lane = tid & 63;
  int lr = lane & 15, lk = lane >> 4;
  int wn = wid*64, wnB = wid*32;
  long m0 = (long)blockIdx.x * 32;

  // ---------------- phase A: fused = attn @ woutT + bout + resid -> FL
  f4_t accA[2][4] = {};
  for (int t=0; t<4; ++t){
    { int c = tid; int r = c>>3, sl = (c&7)^(r&7);               // As 32x64
      gload_lds16(attn + (m0+r)*256 + t*64 + sl*8, R2 + c*8); }
    #pragma unroll
    for (int i=0;i<8;i++){ int c = i*256+tid; int r = c>>3, sl = (c&7)^(r&7);
      gload_lds16(woutT + (long)r*256 + t*64 + sl*8, STG + c*8); }
    __syncthreads();
    #pragma unroll
    for (int ks=0; ks<2; ++ks){
      v8s af[2], bf[4];
      #pragma unroll
      for (int f=0; f<2; f++){ int pr = f*16+lr;
        af[f] = *(const v8s*)(R2 + pr*64 + (((ks*4+lk) ^ (pr&7))*8)); }
      #pragma unroll
      for (int f=0; f<4; f++){ int pr = wn + f*16 + lr;
        bf[f] = *(const v8s*)(STG + pr*64 + (((ks*4+lk) ^ (pr&7))*8)); }
      #pragma unroll
      for (int fm=0; fm<2; fm++)
        #pragma unroll
        for (int fn=0; fn<4; fn++)
          accA[fm][fn] = __builtin_amdgcn_mfma_f32_16x16x32_bf16(bf[fn], af[fm], accA[fm][fn], 0,0,0);
    }
    __syncthreads();
  }
  #pragma unroll
  for (int fm=0; fm<2; fm++){
    int row = fm*16 + lr;
    #pragma unroll
    for (int fn=0; fn<4; fn++){
      int col = wn + fn*16 + lk*4;
      f4_t bv = *(const f4_t*)(bout + col);
      f4_t rv = *(const f4_t*)(resid + (m0+row)*256 + col);
      f4_t v = accA[fm][fn];
      v.x += bv.x + rv.x; v.y += bv.y + rv.y; v.z += bv.z + rv.z; v.w += bv.w + rv.w;
      ushort4 hh; hh.x=f2b(v.x); hh.y=f2b(v.y); hh.z=f2b(v.z); hh.w=f2b(v.w);
      int us = row*256 + (((col>>3) ^ (row&7))*8) + (col&7);
      *(ushort4*)(FL + us) = hh;
    }
  }
  __syncthreads();

  // ---------------- 8 slices: FF1(gelu) -> H(R2) -> FF2 accumulate
  f4_t acc2[2][4] = {};
  for (int s=0; s<8; ++s){
    f4_t accH[2][2] = {};
    for (int t=0; t<4; ++t){
      #pragma unroll
      for (int i=0;i<4;i++){ int c = i*256+tid; int r = c>>3, sl = (c&7)^(r&7);
        gload_lds16(w1T + (long)(s*128+r)*256 + t*64 + sl*8, STG + c*8); }
      __syncthreads();
      #pragma unroll
      for (int ks=0; ks<2; ++ks){
        v8s af[2], bf[2];
        #pragma unroll
        for (int f=0; f<2; f++){ int pr = f*16+lr; int ku = t*8 + ks*4 + lk;
          af[f] = *(const v8s*)(FL + pr*256 + ((ku ^ (pr&7))*8)); }
        #pragma unroll
        for (int f=0; f<2; f++){ int pr = wnB + f*16 + lr;
          bf[f] = *(const v8s*)(STG + pr*64 + (((ks*4+lk) ^ (pr&7))*8)); }
        #pragma unroll
        for (int fm=0; fm<2; fm++)
          #pragma unroll
          for (int fn=0; fn<2; fn++)
            accH[fm][fn] = __builtin_amdgcn_mfma_f32_16x16x32_bf16(bf[fn], af[fm], accH[fm][fn], 0,0,0);
      }
      __syncthreads();
    }
    #pragma unroll
    for (int fm=0; fm<2; fm++){
      int row = fm*16 + lr;
      #pragma unroll
      for (int fn=0; fn<2; fn++){
        int col = wnB + fn*16 + lk*4;                  // 0..127
        f4_t bv = *(const f4_t*)(b1 + s*128 + col);
        f4_t v = accH[fm][fn];
        v.x = geluf(v.x+bv.x); v.y = geluf(v.y+bv.y);
        v.z = geluf(v.z+bv.z); v.w = geluf(v.w+bv.w);
        ushort4 hh; hh.x=f2b(v.x); hh.y=f2b(v.y); hh.z=f2b(v.z); hh.w=f2b(v.w);
        int us = row*128 + (((col>>3) ^ (row&7))*8) + (col&7);
        *(ushort4*)(R2 + us) = hh;
      }
    }
    __syncthreads();
    for (int t=0; t<2; ++t){
      #pragma unroll
      for (int i=0;i<8;i++){ int c = i*256+tid; int r = c>>3, sl = (c&7)^(r&7);
        gload_lds16(w2T + (long)r*1024 + s*128 + t*64 + sl*8, STG + c*8); }
      __syncthreads();
      #pragma unroll
      for (int ks=0; ks<2; ++ks){
        v8s af[2], bf[4];
        #pragma unroll
        for (int f=0; f<2; f++){ int pr = f*16+lr; int ku = t*8 + ks*4 + lk;  // 0..15
          af[f] = *(const v8s*)(R2 + pr*128 + ((ku ^ (pr&7))*8)); }
        #pragma unroll
        for (int f=0; f<4; f++){ int pr = wn + f*16 + lr;
          bf[f] = *(const v8s*)(STG + pr*64 + (((ks*4+lk) ^ (pr&7))*8)); }
        #pragma unroll
        for (int fm=0; fm<2; fm++)
          #pragma unroll
          for (int fn=0; fn<4; fn++)
            acc2[fm][fn] = __builtin_amdgcn_mfma_f32_16x16x32_bf16(bf[fn], af[fm], acc2[fm][fn], 0,0,0);
      }
      __syncthreads();
    }
  }

  // ---------------- phase D: v = acc2 + b2 + fused(FL) ; LN ; store
  f4_t vv[2][4];
  float ps[2], pq[2];
  #pragma unroll
  for (int fm=0; fm<2; fm++){
    int row = fm*16 + lr;
    ps[fm] = 0.0f; pq[fm] = 0.0f;
    #pragma unroll
    for (int fn=0; fn<4; fn++){
      int col = wn + fn*16 + lk*4;
      f4_t bv = *(const f4_t*)(b2 + col);
      int us = row*256 + (((col>>3) ^ (row&7))*8) + (col&7);
      ushort4 fh = *(const ushort4*)(FL + us);
      f4_t v = acc2[fm][fn];
      v.x += bv.x + b2f(fh.x); v.y += bv.y + b2f(fh.y);
      v.z += bv.z + b2f(fh.z); v.w += bv.w + b2f(fh.w);
      vv[fm][fn] = v;
      ps[fm] += v.x+v.y+v.z+v.w;
      pq[fm] += v.x*v.x + v.y*v.y + v.z*v.z + v.w*v.w;
    }
    ps[fm] += __shfl_xor(ps[fm], 16); ps[fm] += __shfl_xor(ps[fm], 32);
    pq[fm] += __shfl_xor(pq[fm], 16); pq[fm] += __shfl_xor(pq[fm], 32);
  }
  float* PS = (float*)R2;          // [32][4]
  float* PQ = (float*)R2 + 128;    // [32][4]
  if (lk == 0){
    #pragma unroll
    for (int fm=0; fm<2; fm++){ int row = fm*16+lr;
      PS[row*4 + wid] = ps[fm]; PQ[row*4 + wid] = pq[fm]; }
  }
  __syncthreads();
  #pragma unroll
  for (int fm=0; fm<2; fm++){
    int row = fm*16 + lr;
    f4_t sv = *(const f4_t*)(PS + row*4);
    f4_t qv = *(const f4_t*)(PQ + row*4);
    float S = sv.x+sv.y+sv.z+sv.w, Q = qv.x+qv.y+qv.z+qv.w;
    float mean = S*(1.0f/256.0f);
    float rstd = rsqrtf(Q*(1.0f/256.0f) - mean*mean + 1e-5f);
    #pragma unroll
    for (int fn=0; fn<4; fn++){
      int col = wn + fn*16 + lk*4;
      f4_t G = *(const f4_t*)(fg + col);
      f4_t Bb = *(const f4_t*)(fb + col);
      f4_t v = vv[fm][fn], o;
      o.x = (v.x-mean)*rstd*G.x + Bb.x;
      o.y = (v.y-mean)*rstd*G.y + Bb.y;
      o.z = (v.z-mean)*rstd*G.z + Bb.z;
      o.w = (v.w-mean)*rstd*G.w + Bb.w;
      *(f4_t*)(dout + (m0+row)*256 + col) = o;
    }
  }
}

// ---------------------------------------------------------------- host ----
extern "C" void kernel_launch(void* const* d_in, const int* in_sizes, int n_in,
                              void* d_out, int out_size, void* d_ws, size_t ws_size,
                              hipStream_t stream)
{
  const float* f24    = (const float*)d_in[0];
  const float* f77    = (const float*)d_in[1];
  const float* fx     = (const float*)d_in[2];
  const float* norm_g = (const float*)d_in[3];
  const float* norm_b = (const float*)d_in[4];
  const float* Wq24 = (const float*)d_in[5];  const float* bq24 = (const float*)d_in[6];
  const float* Wk24 = (const float*)d_in[7];  const float* bk24 = (const float*)d_in[8];
  const float* Wv24 = (const float*)d_in[9];  const float* bv24 = (const float*)d_in[10];
  const float* Wq77 = (const float*)d_in[11]; const float* bq77 = (const float*)d_in[12];
  const float* Wk77 = (const float*)d_in[13]; const float* bk77 = (const float*)d_in[14];
  const float* Wv77 = (const float*)d_in[15]; const float* bv77 = (const float*)d_in[16];
  const float* Wqx  = (const float*)d_in[17]; const float* bqx  = (const float*)d_in[18];
  const float* Wkx  = (const float*)d_in[19]; const float* bkx  = (const float*)d_in[20];
  const float* Wvx  = (const float*)d_in[21]; const float* bvx  = (const float*)d_in[22];
  const float* Wout = (const float*)d_in[23]; const float* bout = (const float*)d_in[24];
  const float* radar_w = (const float*)d_in[25];
  const float* W1 = (const float*)d_in[26];   const float* b1 = (const float*)d_in[27];
  const float* W2 = (const float*)d_in[28];   const float* b2 = (const float*)d_in[29];
  const float* fnorm_g = (const float*)d_in[30];
  const float* fnorm_b = (const float*)d_in[31];

  const long Brows = (long)in_sizes[0] / 256;   // 131072
  float* dout = (float*)d_out;
  char* ws = (char*)d_ws;

  // ---- fixed (weights) region ----
  size_t off = 0;
  auto A_ = [&](size_t b){ size_t o = off; off = (off + b + 255) & ~(size_t)255; return o; };
  size_t oWT = A_((size_t)3*768*256*2);
  size_t oWO = A_((size_t)65536*2);
  size_t oW1 = A_((size_t)262144*2);
  size_t oW2 = A_((size_t)262144*2);
  size_t oBC = A_((size_t)2304*4);
  size_t oRW = A_(256);
  size_t fixedEnd = off;

  unsigned short* WT_CAT = (unsigned short*)(ws + oWT);
  unsigned short* WOUT_T = (unsigned short*)(ws + oWO);
  unsigned short* W1_T   = (unsigned short*)(ws + oW1);
  unsigned short* W2_T   = (unsigned short*)(ws + oW2);
  float*          BIASC  = (float*)(ws + oBC);
  float*          RW     = (float*)(ws + oRW);

  // ---- adaptive chunking over rows ----
  // per-row bytes: NBUF 3*256*2=1536 | RESID 256*4=1024 | QKV 3*768*2=4608
  const size_t PER_ROW = 7168;
  if (ws_size <= fixedEnd + 512) return;
  long maxR = (long)((ws_size - fixedEnd - 256) / PER_ROW);
  maxR &= ~127L;
  if (maxR < 128) return;
  long Rc = maxR < 65536 ? maxR : 65536;       // fewer chunks -> fewer dispatch tails
  if (Rc > Brows) Rc = Brows;
  long nch = (Brows + Rc - 1) / Rc;
  Rc = ((Brows + nch - 1) / nch + 127) & ~127L;

  size_t chunkBase = (fixedEnd + 255) & ~(size_t)255;
  char* NB_B = ws + chunkBase;                              // 1536*Rc
  char* RS_B = NB_B + (size_t)1536*Rc;                      // 1024*Rc
  char* QK_B = RS_B + (size_t)1024*Rc;                      // 4608*Rc

  { // prep: weight transposes + bias concat + rw (also writes d_out tail)
    long total = 589824 + 65536 + 262144 + 262144 + 2304 + 3;
    int blocks = (int)((total + 255) / 256);
    k_prep<<<blocks, 256, 0, stream>>>(
        Wq24, Wk24, Wv24, Wq77, Wk77, Wv77, Wqx, Wkx, Wvx,
        bq24, bk24, bv24, bq77, bk77, bv77, bqx, bkx, bvx,
        Wout, W1, W2, radar_w,
        WT_CAT, WOUT_T, W1_T, W2_T, BIASC, RW, dout + (size_t)Brows*256);
  }

  for (long row0 = 0; row0 < Brows; row0 += Rc){
    long rows = Brows - row0 < Rc ? Brows - row0 : Rc;   // multiple of 128
    unsigned short* NBUF   = (unsigned short*)NB_B;
    float*          RESID  = (float*)RS_B;
    unsigned short* QKV    = (unsigned short*)QK_B;
    unsigned short* ATTN   = (unsigned short*)NB_B;      // alias (nbuf dead after gemm0)

    int tM = (int)(rows/128);

    k_ln3<<<(int)(rows/4), 256, 0, stream>>>(
        f24 + row0*256, f77 + row0*256, fx + row0*256,
        norm_g, norm_b, NBUF, RESID, (int)rows);

    { int tiles = tM*6*3; int grid = tiles < 512 ? tiles : 512;
      k_gemm256<0><<<grid, 256, 0, stream>>>(
          NBUF, WT_CAT, BIASC, QKV,
          rows*256L, 768L*256, 768L, rows*768L, 768, tM, 6, 3); }

    k_attn<<<(int)(rows/8), 512, 0, stream>>>(QKV, RW, ATTN, (int)rows);

    k_back<<<(int)(rows/32), 256, 0, stream>>>(
        ATTN, RESID, WOUT_T, W1_T, W2_T,
        bout, b1, b2, fnorm_g, fnorm_b, dout + row0*256);
  }
}

// Round 10
// 1404.689 us; speedup vs baseline: 1.4160x; 1.1484x over previous
//
#include <hip/hip_runtime.h>

#define DEV __device__ __forceinline__

typedef float f4_t __attribute__((ext_vector_type(4)));
typedef short v8s  __attribute__((ext_vector_type(8)));

DEV float lo16(unsigned int w){ return __uint_as_float(w << 16); }
DEV float hi16(unsigned int w){ return __uint_as_float(w & 0xffff0000u); }
DEV float b2f(unsigned short u){ return __uint_as_float((unsigned)u << 16); }
DEV unsigned short f2b(float f){
  unsigned int x = __float_as_uint(f);
  x += 0x7fffu + ((x >> 16) & 1u);     // round-to-nearest-even (finite values)
  return (unsigned short)(x >> 16);
}
DEV float geluf(float v){ return 0.5f * v * (1.0f + erff(v * 0.7071067811865475f)); }

DEV void gload_lds16(const unsigned short* g, unsigned short* l){
  __builtin_amdgcn_global_load_lds(
      (const __attribute__((address_space(1))) void*)g,
      (__attribute__((address_space(3))) void*)l, 16, 0, 0);
}

#define WAITV(n) asm volatile("s_waitcnt vmcnt(" #n ")" ::: "memory")
#define SBAR()  do{ __builtin_amdgcn_sched_barrier(0); \
                    asm volatile("s_barrier" ::: "memory"); \
                    __builtin_amdgcn_sched_barrier(0); }while(0)

// ---------------------------------------------------------------- prep ----
__global__ void k_prep(
    const float* Wq24, const float* Wk24, const float* Wv24,
    const float* Wq77, const float* Wk77, const float* Wv77,
    const float* Wqx,  const float* Wkx,  const float* Wvx,
    const float* bq24, const float* bk24, const float* bv24,
    const float* bq77, const float* bk77, const float* bv77,
    const float* bqx,  const float* bkx,  const float* bvx,
    const float* Wout, const float* W1,   const float* W2,
    const float* radar_w,
    unsigned short* wt_cat, unsigned short* wout_t,
    unsigned short* w1_t, unsigned short* w2_t,
    float* bias_cat, float* rwbuf, float* out_tail)
{
  long idx = (long)blockIdx.x * blockDim.x + threadIdx.x;
  if (idx < 589824){                       // Wt_cat[3][768][256] = W[k][n] -> [n][k] bf16
    int s = (int)(idx / 196608);
    int r = (int)(idx % 196608);
    int ng = r >> 8, k = r & 255;
    int which = ng >> 8, n = ng & 255;
    const float* src;
    switch (s*3 + which){
      case 0: src = Wq24; break;  case 1: src = Wk24; break;  case 2: src = Wv24; break;
      case 3: src = Wq77; break;  case 4: src = Wk77; break;  case 5: src = Wv77; break;
      case 6: src = Wqx;  break;  case 7: src = Wkx;  break;  default: src = Wvx; break;
    }
    wt_cat[idx] = f2b(src[k*256 + n]);
    return;
  }
  idx -= 589824;
  if (idx < 65536){ int n = (int)(idx >> 8), k = (int)(idx & 255);
    wout_t[idx] = f2b(Wout[k*256 + n]); return; }
  idx -= 65536;
  if (idx < 262144){ int n = (int)(idx >> 8), k = (int)(idx & 255);   // W1t[1024][256]
    w1_t[idx] = f2b(W1[k*1024 + n]); return; }
  idx -= 262144;
  if (idx < 262144){ int n = (int)(idx >> 10), k = (int)(idx & 1023); // W2t[256][1024]
    w2_t[idx] = f2b(W2[k*256 + n]); return; }
  idx -= 262144;
  if (idx < 2304){
    int s = (int)(idx / 768), j = (int)(idx % 768);
    int which = j >> 8, jj = j & 255;
    const float* src;
    switch (s*3 + which){
      case 0: src = bq24; break;  case 1: src = bk24; break;  case 2: src = bv24; break;
      case 3: src = bq77; break;  case 4: src = bk77; break;  case 5: src = bv77; break;
      case 6: src = bqx;  break;  case 7: src = bkx;  break;  default: src = bvx; break;
    }
    bias_cat[idx] = src[jj]; return;
  }
  idx -= 2304;
  if (idx < 3){
    float w0 = radar_w[0], w1v = radar_w[1], w2v = radar_w[2];
    float m = fmaxf(w0, fmaxf(w1v, w2v));
    float e0 = __expf(w0-m), e1 = __expf(w1v-m), e2 = __expf(w2v-m);
    float inv = 1.0f/(e0+e1+e2);
    float rw = (idx==0 ? e0 : (idx==1 ? e1 : e2)) * inv;
    rwbuf[idx] = rw; out_tail[idx] = rw;
  }
}

// --------------------------------------------------------------- 3x LN ----
__global__ __launch_bounds__(256) void k_ln3(
    const float* __restrict__ f24, const float* __restrict__ f77, const float* __restrict__ fx,
    const float* __restrict__ gg, const float* __restrict__ bb,
    unsigned short* __restrict__ nbuf, float* __restrict__ resid, int rows)
{
  int wid = threadIdx.x >> 6, lane = threadIdx.x & 63;
  long row = (long)blockIdx.x*4 + wid;
  long base = row*256 + lane*4;
  f4_t x0 = *(const f4_t*)(f24 + base);
  f4_t x1 = *(const f4_t*)(f77 + base);
  f4_t x2 = *(const f4_t*)(fx  + base);
  float s[3], q[3];
  s[0]=x0.x+x0.y+x0.z+x0.w;
  s[1]=x1.x+x1.y+x1.z+x1.w;
  s[2]=x2.x+x2.y+x2.z+x2.w;
  q[0]=fmaf(x0.x,x0.x,fmaf(x0.y,x0.y,fmaf(x0.z,x0.z,x0.w*x0.w)));
  q[1]=fmaf(x1.x,x1.x,fmaf(x1.y,x1.y,fmaf(x1.z,x1.z,x1.w*x1.w)));
  q[2]=fmaf(x2.x,x2.x,fmaf(x2.y,x2.y,fmaf(x2.z,x2.z,x2.w*x2.w)));
  #pragma unroll
  for (int m=1;m<64;m<<=1){
    #pragma unroll
    for (int j=0;j<3;j++){ s[j]+=__shfl_xor(s[j],m); q[j]+=__shfl_xor(q[j],m); }
  }
  f4_t G  = *(const f4_t*)(gg + lane*4);
  f4_t Bv = *(const f4_t*)(bb + lane*4);
  long strm = (long)rows*256;
  {
    float mean = s[0]*(1.0f/256.0f);
    float rstd = rsqrtf(q[0]*(1.0f/256.0f) - mean*mean + 1e-5f);
    ushort4 o;
    o.x=f2b((x0.x-mean)*rstd*G.x+Bv.x); o.y=f2b((x0.y-mean)*rstd*G.y+Bv.y);
    o.z=f2b((x0.z-mean)*rstd*G.z+Bv.z); o.w=f2b((x0.w-mean)*rstd*G.w+Bv.w);
    *(ushort4*)(nbuf + base) = o;
  }
  {
    float mean = s[1]*(1.0f/256.0f);
    float rstd = rsqrtf(q[1]*(1.0f/256.0f) - mean*mean + 1e-5f);
    ushort4 o;
    o.x=f2b((x1.x-mean)*rstd*G.x+Bv.x); o.y=f2b((x1.y-mean)*rstd*G.y+Bv.y);
    o.z=f2b((x1.z-mean)*rstd*G.z+Bv.z); o.w=f2b((x1.w-mean)*rstd*G.w+Bv.w);
    *(ushort4*)(nbuf + strm + base) = o;
  }
  {
    float mean = s[2]*(1.0f/256.0f);
    float rstd = rsqrtf(q[2]*(1.0f/256.0f) - mean*mean + 1e-5f);
    ushort4 o;
    o.x=f2b((x2.x-mean)*rstd*G.x+Bv.x); o.y=f2b((x2.y-mean)*rstd*G.y+Bv.y);
    o.z=f2b((x2.z-mean)*rstd*G.z+Bv.z); o.w=f2b((x2.w-mean)*rstd*G.w+Bv.w);
    *(ushort4*)(nbuf + 2*strm + base) = o;
  }
  f4_t rs;
  rs.x=(x0.x+x1.x+x2.x)*(1.0f/3.0f);
  rs.y=(x0.y+x1.y+x2.y)*(1.0f/3.0f);
  rs.z=(x0.z+x1.z+x2.z)*(1.0f/3.0f);
  rs.w=(x0.w+x1.w+x2.w)*(1.0f/3.0f);
  *(f4_t*)(resid + base) = rs;
}

// ------------------------------------------------- QKV GEMM (R7 form) ----
template<int EPI>
__global__ __launch_bounds__(256,2) void k_gemm256(
    const unsigned short* __restrict__ A, const unsigned short* __restrict__ Bt,
    const float* __restrict__ bias,
    unsigned short* __restrict__ outH,
    long aBatch, long bBatch, long biasBatch, long oBatch, int ldOut,
    int tM, int tN, int tZ)
{
  __shared__ __align__(16) unsigned short As[2][128][64];
  __shared__ __align__(16) unsigned short Bs[2][128][64];
  int tid = threadIdx.x, wid = tid >> 6, lane = tid & 63;
  int wm = (wid >> 1)*64, wn = (wid & 1)*64;
  int lr = lane & 15, lk = lane >> 4;

  int total = tM*tN*tZ;
  int nT = (total - (int)blockIdx.x + (int)gridDim.x - 1) / (int)gridDim.x;
  if (nT <= 0) return;
  int G = nT*4;

  auto tileOf = [&](int j, long& m0, int& n0, int& z){
    int T = (int)blockIdx.x + j*(int)gridDim.x;
    int mt = T % tM; int rest = T / tM;
    int nt = rest % tN; z = rest / tN;
    m0 = (long)mt*128; n0 = nt*128;
  };

  auto stage = [&](int g){
    long m0; int n0, z;
    tileOf(g >> 2, m0, n0, z);
    int k0 = (g & 3)*64, bi = g & 1;
    const unsigned short* Ab = A  + (long)z*aBatch + m0*256;
    const unsigned short* Bb = Bt + (long)z*bBatch + (long)n0*256;
    #pragma unroll
    for (int i=0;i<4;i++){
      int c = (wid*4+i)*64 + lane;
      int r = c >> 3, sl = (c & 7) ^ (r & 7);          // pre-swizzled source
      gload_lds16(Ab + (long)r*256 + k0 + sl*8, &As[bi][0][0] + (long)(wid*4+i)*512);
      gload_lds16(Bb + (long)r*256 + k0 + sl*8, &Bs[bi][0][0] + (long)(wid*4+i)*512);
    }
  };

  const f4_t fz = {0.f,0.f,0.f,0.f};
  f4_t acc[4][4] = {};

  stage(0);
  for (int g=0; g<G; ++g){
    if (g+1 < G){ stage(g+1); WAITV(8); }
    else        { WAITV(0); }
    SBAR();
    int cur = g & 1;
    #pragma unroll
    for (int ks=0; ks<2; ++ks){
      v8s af[4], bfv[4];
      #pragma unroll
      for (int f=0; f<4; f++){
        int prA = wm + f*16 + lr;
        int prB = wn + f*16 + lr;
        int js  = ks*4 + lk;
        af[f]  = *(const v8s*)&As[cur][prA][(js ^ (prA & 7))*8];   // swizzled read
        bfv[f] = *(const v8s*)&Bs[cur][prB][(js ^ (prB & 7))*8];
      }
      #pragma unroll
      for (int fm=0; fm<4; fm++)
        #pragma unroll
        for (int fn=0; fn<4; fn++)
          acc[fm][fn] = __builtin_amdgcn_mfma_f32_16x16x32_bf16(bfv[fn], af[fm], acc[fm][fn], 0,0,0);
    }
    if ((g & 3) == 3){
      long m0; int n0, z;
      tileOf(g >> 2, m0, n0, z);
      long zo = (long)z*oBatch;
      const float* bp = bias + (long)z*biasBatch;
      #pragma unroll
      for (int fm=0; fm<4; fm++){
        long gm = m0 + wm + fm*16 + lr;                 // lane owns this row
        long rowo = zo + gm*(long)ldOut;
        #pragma unroll
        for (int fn=0; fn<4; fn++){
          int gn = n0 + wn + fn*16 + lk*4;              // 4 consecutive cols
          f4_t bv = *(const f4_t*)(bp + gn);
          f4_t v = acc[fm][fn];
          v.x += bv.x; v.y += bv.y; v.z += bv.z; v.w += bv.w;
          ushort4 o; o.x=f2b(v.x); o.y=f2b(v.y); o.z=f2b(v.z); o.w=f2b(v.w);
          *(ushort4*)(outH + rowo + gn) = o;
          acc[fm][fn] = fz;                             // reset for next tile
        }
      }
    }
    SBAR();
  }
}

// ---------------------------------------------------- per-row attention ----
// Pipelined: grid-stride over 8-row tiles, double-buffered LDS staged via
// global_load_lds (linear [8][72][32] layout, wave-uniform dest base), counted
// vmcnt(5) so next-tile loads stay in flight across barriers. One wave/row.
__global__ __launch_bounds__(512,4) void k_attn(
    const unsigned short* __restrict__ qkv, const float* __restrict__ rwb,
    unsigned short* __restrict__ outA, int rows)
{
  __shared__ __align__(16) unsigned short L[2][8][72][32];   // 72 KB
  int tid = threadIdx.x, wid = tid >> 6, lane = tid & 63;
  int nT = rows >> 3;
  int t0 = blockIdx.x;
  if (t0 >= nT) return;

  auto stage = [&](int b, int tile){
    long brow0 = (long)tile*8;
    unsigned short* Lb = &L[b][0][0][0];
    #pragma unroll
    for (int it=0; it<5; ++it){
      int cw = it*512 + wid*64;          // wave-uniform chunk base
      if (cw < 2304){
        int c = cw + lane;               // per-lane global index
        int row = c/288, rem = c - row*288;
        int s = rem/96,  cc  = rem - s*96;
        gload_lds16(qkv + ((long)s*rows + brow0 + row)*768 + cc*8,
                    Lb + (long)cw*8);    // HW adds lane*16B
      }
    }
  };

  float rw0 = rwb[0], rw1 = rwb[1], rw2 = rwb[2];
  int h = lane >> 3, g = lane & 7;

  stage(0, t0);
  int pb = 0;
  for (int t = t0; t < nT; t += (int)gridDim.x){
    SBAR();                              // all waves done reading L[pb^1]
    int tn = t + (int)gridDim.x;
    if (tn < nT){ stage(pb^1, tn); WAITV(5); }
    else        { WAITV(0); }
    SBAR();                              // L[pb] complete for all waves

    const unsigned short* R = &L[pb][wid][0][0];
    float comb[32];
    #pragma unroll
    for (int i=0;i<32;i++) comb[i] = 0.0f;

    #pragma unroll
    for (int att=0; att<3; ++att){
      int qs  = att;
      int as_ = (att==0) ? 1 : 0;
      int bs_ = (att==2) ? 1 : 2;
      float rwv = (att==0) ? rw0 : ((att==1) ? rw1 : rw2);
      const unsigned short* qp  = R + (qs *24      + h)*32;
      const unsigned short* kap = R + (as_*24 + 8  + g)*32;
      const unsigned short* kbp = R + (bs_*24 + 8  + g)*32;
      float a0=0.f, a1=0.f, b0=0.f, b1=0.f;   // 2-way split: half dep-chain
      #pragma unroll
      for (int j=0;j<4;j++){
        uint4 qc  = *(const uint4*)(qp  + j*8);
        uint4 kac = *(const uint4*)(kap + j*8);
        uint4 kbc = *(const uint4*)(kbp + j*8);
        float* ap = (j&1) ? &a1 : &a0;
        float* bp = (j&1) ? &b1 : &b0;
        #define DOT2(QW,KA,KB) { float q0=lo16(QW), q1=hi16(QW); \
          *ap=fmaf(q0,lo16(KA),*ap); *ap=fmaf(q1,hi16(KA),*ap); \
          *bp=fmaf(q0,lo16(KB),*bp); *bp=fmaf(q1,hi16(KB),*bp); }
        DOT2(qc.x, kac.x, kbc.x) DOT2(qc.y, kac.y, kbc.y)
        DOT2(qc.z, kac.z, kbc.z) DOT2(qc.w, kac.w, kbc.w)
        #undef DOT2
      }
      float d  = ((b0+b1) - (a0+a1)) * 0.17677669529663689f;   // * 1/sqrt(32)
      float p0 = 1.0f / (1.0f + __expf(d));
      float p1 = 1.0f - p0;
      float w0 = rwv * p0, w1 = rwv * p1;
      const unsigned short* vap = R + (as_*24 + 16 + g)*32;
      const unsigned short* vbp = R + (bs_*24 + 16 + g)*32;
      #pragma unroll
      for (int j=0;j<4;j++){
        uint4 va = *(const uint4*)(vap + j*8);
        uint4 vb = *(const uint4*)(vbp + j*8);
        #define MIX2(VA,VB,C0,C1) { \
          C0 = fmaf(w0, lo16(VA), fmaf(w1, lo16(VB), C0)); \
          C1 = fmaf(w0, hi16(VA), fmaf(w1, hi16(VB), C1)); }
        MIX2(va.x, vb.x, comb[j*8+0], comb[j*8+1])
        MIX2(va.y, vb.y, comb[j*8+2], comb[j*8+3])
        MIX2(va.z, vb.z, comb[j*8+4], comb[j*8+5])
        MIX2(va.w, vb.w, comb[j*8+6], comb[j*8+7])
        #undef MIX2
      }
    }

    // reduce-scatter over g (xor 4,2,1): lane (h,g) ends with d = g*4..g*4+3
    float t16[16];
    { bool up = (lane & 4) != 0;
      #pragma unroll
      for (int i=0;i<16;i++){
        float send = up ? comb[i] : comb[16+i];
        float keep = up ? comb[16+i] : comb[i];
        t16[i] = keep + __shfl_xor(send, 4);
      } }
    float t8[8];
    { bool up = (lane & 2) != 0;
      #pragma unroll
      for (int i=0;i<8;i++){
        float send = up ? t16[i] : t16[8+i];
        float keep = up ? t16[8+i] : t16[i];
        t8[i] = keep + __shfl_xor(send, 2);
      } }
    float t4[4];
    { bool up = (lane & 1) != 0;
      #pragma unroll
      for (int i=0;i<4;i++){
        float send = up ? t8[i] : t8[4+i];
        float keep = up ? t8[4+i] : t8[i];
        t4[i] = keep + __shfl_xor(send, 1);
      } }

    long orow = (long)t*8 + wid;
    ushort4 o4;
    o4.x = f2b(t4[0]); o4.y = f2b(t4[1]); o4.z = f2b(t4[2]); o4.w = f2b(t4[3]);
    *(ushort4*)(outA + orow*256 + lane*4) = o4;
    pb ^= 1;
  }
}

// ------------------- fused backend: Wout+resid -> FF1+gelu -> FF2 -> LN ----
// BM=32 rows/block, 256 threads (4 waves), 56KB LDS -> 2 blocks/CU.
__global__ __launch_bounds__(256,2) void k_back(
    const unsigned short* __restrict__ attn,  // chunk [rows][256] bf16
    const float* __restrict__ resid,          // chunk [rows][256] f32
    const unsigned short* __restrict__ woutT, // [256][256]
    const unsigned short* __restrict__ w1T,   // [1024][256]
    const unsigned short* __restrict__ w2T,   // [256][1024]
    const float* __restrict__ bout, const float* __restrict__ b1,
    const float* __restrict__ b2,
    const float* __restrict__ fg, const float* __restrict__ fb,
    float* __restrict__ dout)                 // chunk [rows][256] f32
{
  __shared__ __align__(16) unsigned short FL[8192];    // fused bf16 [32][256] swz
  __shared__ __align__(16) unsigned short STG[16384];  // B staging [<=256][64] swz
  __shared__ __align__(16) unsigned short R2[4096];    // As / HLDS[32][128] / partials
  int tid = threadIdx.x, wid = tid >> 6, lane = tid & 63;
  int lr = lane & 15, lk = lane >> 4;
  int wn = wid*64, wnB = wid*32;
  long m0 = (long)blockIdx.x * 32;

  // ---------------- phase A: fused = attn @ woutT + bout + resid -> FL
  f4_t accA[2][4] = {};
  for (int t=0; t<4; ++t){
    { int c = tid; int r = c>>3, sl = (c&7)^(r&7);               // As 32x64
      gload_lds16(attn + (m0+r)*256 + t*64 + sl*8, R2 + c*8); }
    #pragma unroll
    for (int i=0;i<8;i++){ int c = i*256+tid; int r = c>>3, sl = (c&7)^(r&7);
      gload_lds16(woutT + (long)r*256 + t*64 + sl*8, STG + c*8); }
    __syncthreads();
    #pragma unroll
    for (int ks=0; ks<2; ++ks){
      v8s af[2], bf[4];
      #pragma unroll
      for (int f=0; f<2; f++){ int pr = f*16+lr;
        af[f] = *(const v8s*)(R2 + pr*64 + (((ks*4+lk) ^ (pr&7))*8)); }
      #pragma unroll
      for (int f=0; f<4; f++){ int pr = wn + f*16 + lr;
        bf[f] = *(const v8s*)(STG + pr*64 + (((ks*4+lk) ^ (pr&7))*8)); }
      #pragma unroll
      for (int fm=0; fm<2; fm++)
        #pragma unroll
        for (int fn=0; fn<4; fn++)
          accA[fm][fn] = __builtin_amdgcn_mfma_f32_16x16x32_bf16(bf[fn], af[fm], accA[fm][fn], 0,0,0);
    }
    __syncthreads();
  }
  #pragma unroll
  for (int fm=0; fm<2; fm++){
    int row = fm*16 + lr;
    #pragma unroll
    for (int fn=0; fn<4; fn++){
      int col = wn + fn*16 + lk*4;
      f4_t bv = *(const f4_t*)(bout + col);
      f4_t rv = *(const f4_t*)(resid + (m0+row)*256 + col);
      f4_t v = accA[fm][fn];
      v.x += bv.x + rv.x; v.y += bv.y + rv.y; v.z += bv.z + rv.z; v.w += bv.w + rv.w;
      ushort4 hh; hh.x=f2b(v.x); hh.y=f2b(v.y); hh.z=f2b(v.z); hh.w=f2b(v.w);
      int us = row*256 + (((col>>3) ^ (row&7))*8) + (col&7);
      *(ushort4*)(FL + us) = hh;
    }
  }
  __syncthreads();

  // ---------------- 8 slices: FF1(gelu) -> H(R2) -> FF2 accumulate
  f4_t acc2[2][4] = {};
  for (int s=0; s<8; ++s){
    f4_t accH[2][2] = {};
    for (int t=0; t<4; ++t){
      #pragma unroll
      for (int i=0;i<4;i++){ int c = i*256+tid; int r = c>>3, sl = (c&7)^(r&7);
        gload_lds16(w1T + (long)(s*128+r)*256 + t*64 + sl*8, STG + c*8); }
      __syncthreads();
      #pragma unroll
      for (int ks=0; ks<2; ++ks){
        v8s af[2], bf[2];
        #pragma unroll
        for (int f=0; f<2; f++){ int pr = f*16+lr; int ku = t*8 + ks*4 + lk;
          af[f] = *(const v8s*)(FL + pr*256 + ((ku ^ (pr&7))*8)); }
        #pragma unroll
        for (int f=0; f<2; f++){ int pr = wnB + f*16 + lr;
          bf[f] = *(const v8s*)(STG + pr*64 + (((ks*4+lk) ^ (pr&7))*8)); }
        #pragma unroll
        for (int fm=0; fm<2; fm++)
          #pragma unroll
          for (int fn=0; fn<2; fn++)
            accH[fm][fn] = __builtin_amdgcn_mfma_f32_16x16x32_bf16(bf[fn], af[fm], accH[fm][fn], 0,0,0);
      }
      __syncthreads();
    }
    #pragma unroll
    for (int fm=0; fm<2; fm++){
      int row = fm*16 + lr;
      #pragma unroll
      for (int fn=0; fn<2; fn++){
        int col = wnB + fn*16 + lk*4;                  // 0..127
        f4_t bv = *(const f4_t*)(b1 + s*128 + col);
        f4_t v = accH[fm][fn];
        v.x = geluf(v.x+bv.x); v.y = geluf(v.y+bv.y);
        v.z = geluf(v.z+bv.z); v.w = geluf(v.w+bv.w);
        ushort4 hh; hh.x=f2b(v.x); hh.y=f2b(v.y); hh.z=f2b(v.z); hh.w=f2b(v.w);
        int us = row*128 + (((col>>3) ^ (row&7))*8) + (col&7);
        *(ushort4*)(R2 + us) = hh;
      }
    }
    __syncthreads();
    for (int t=0; t<2; ++t){
      #pragma unroll
      for (int i=0;i<8;i++){ int c = i*256+tid; int r = c>>3, sl = (c&7)^(r&7);
        gload_lds16(w2T + (long)r*1024 + s*128 + t*64 + sl*8, STG + c*8); }
      __syncthreads();
      #pragma unroll
      for (int ks=0; ks<2; ++ks){
        v8s af[2], bf[4];
        #pragma unroll
        for (int f=0; f<2; f++){ int pr = f*16+lr; int ku = t*8 + ks*4 + lk;  // 0..15
          af[f] = *(const v8s*)(R2 + pr*128 + ((ku ^ (pr&7))*8)); }
        #pragma unroll
        for (int f=0; f<4; f++){ int pr = wn + f*16 + lr;
          bf[f] = *(const v8s*)(STG + pr*64 + (((ks*4+lk) ^ (pr&7))*8)); }
        #pragma unroll
        for (int fm=0; fm<2; fm++)
          #pragma unroll
          for (int fn=0; fn<4; fn++)
            acc2[fm][fn] = __builtin_amdgcn_mfma_f32_16x16x32_bf16(bf[fn], af[fm], acc2[fm][fn], 0,0,0);
      }
      __syncthreads();
    }
  }

  // ---------------- phase D: v = acc2 + b2 + fused(FL) ; LN ; store
  f4_t vv[2][4];
  float ps[2], pq[2];
  #pragma unroll
  for (int fm=0; fm<2; fm++){
    int row = fm*16 + lr;
    ps[fm] = 0.0f; pq[fm] = 0.0f;
    #pragma unroll
    for (int fn=0; fn<4; fn++){
      int col = wn + fn*16 + lk*4;
      f4_t bv = *(const f4_t*)(b2 + col);
      int us = row*256 + (((col>>3) ^ (row&7))*8) + (col&7);
      ushort4 fh = *(const ushort4*)(FL + us);
      f4_t v = acc2[fm][fn];
      v.x += bv.x + b2f(fh.x); v.y += bv.y + b2f(fh.y);
      v.z += bv.z + b2f(fh.z); v.w += bv.w + b2f(fh.w);
      vv[fm][fn] = v;
      ps[fm] += v.x+v.y+v.z+v.w;
      pq[fm] += v.x*v.x + v.y*v.y + v.z*v.z + v.w*v.w;
    }
    ps[fm] += __shfl_xor(ps[fm], 16); ps[fm] += __shfl_xor(ps[fm], 32);
    pq[fm] += __shfl_xor(pq[fm], 16); pq[fm] += __shfl_xor(pq[fm], 32);
  }
  float* PS = (float*)R2;          // [32][4]
  float* PQ = (float*)R2 + 128;    // [32][4]
  if (lk == 0){
    #pragma unroll
    for (int fm=0; fm<2; fm++){ int row = fm*16+lr;
      PS[row*4 + wid] = ps[fm]; PQ[row*4 + wid] = pq[fm]; }
  }
  __syncthreads();
  #pragma unroll
  for (int fm=0; fm<2; fm++){
    int row = fm*16 + lr;
    f4_t sv = *(const f4_t*)(PS + row*4);
    f4_t qv = *(const f4_t*)(PQ + row*4);
    float S = sv.x+sv.y+sv.z+sv.w, Q = qv.x+qv.y+qv.z+qv.w;
    float mean = S*(1.0f/256.0f);
    float rstd = rsqrtf(Q*(1.0f/256.0f) - mean*mean + 1e-5f);
    #pragma unroll
    for (int fn=0; fn<4; fn++){
      int col = wn + fn*16 + lk*4;
      f4_t G = *(const f4_t*)(fg + col);
      f4_t Bb = *(const f4_t*)(fb + col);
      f4_t v = vv[fm][fn], o;
      o.x = (v.x-mean)*rstd*G.x + Bb.x;
      o.y = (v.y-mean)*rstd*G.y + Bb.y;
      o.z = (v.z-mean)*rstd*G.z + Bb.z;
      o.w = (v.w-mean)*rstd*G.w + Bb.w;
      *(f4_t*)(dout + (m0+row)*256 + col) = o;
    }
  }
}

// ---------------------------------------------------------------- host ----
extern "C" void kernel_launch(void* const* d_in, const int* in_sizes, int n_in,
                              void* d_out, int out_size, void* d_ws, size_t ws_size,
                              hipStream_t stream)
{
  const float* f24    = (const float*)d_in[0];
  const float* f77    = (const float*)d_in[1];
  const float* fx     = (const float*)d_in[2];
  const float* norm_g = (const float*)d_in[3];
  const float* norm_b = (const float*)d_in[4];
  const float* Wq24 = (const float*)d_in[5];  const float* bq24 = (const float*)d_in[6];
  const float* Wk24 = (const float*)d_in[7];  const float* bk24 = (const float*)d_in[8];
  const float* Wv24 = (const float*)d_in[9];  const float* bv24 = (const float*)d_in[10];
  const float* Wq77 = (const float*)d_in[11]; const float* bq77 = (const float*)d_in[12];
  const float* Wk77 = (const float*)d_in[13]; const float* bk77 = (const float*)d_in[14];
  const float* Wv77 = (const float*)d_in[15]; const float* bv77 = (const float*)d_in[16];
  const float* Wqx  = (const float*)d_in[17]; const float* bqx  = (const float*)d_in[18];
  const float* Wkx  = (const float*)d_in[19]; const float* bkx  = (const float*)d_in[20];
  const float* Wvx  = (const float*)d_in[21]; const float* bvx  = (const float*)d_in[22];
  const float* Wout = (const float*)d_in[23]; const float* bout = (const float*)d_in[24];
  const float* radar_w = (const float*)d_in[25];
  const float* W1 = (const float*)d_in[26];   const float* b1 = (const float*)d_in[27];
  const float* W2 = (const float*)d_in[28];   const float* b2 = (const float*)d_in[29];
  const float* fnorm_g = (const float*)d_in[30];
  const float* fnorm_b = (const float*)d_in[31];

  const long Brows = (long)in_sizes[0] / 256;   // 131072
  float* dout = (float*)d_out;
  char* ws = (char*)d_ws;

  // ---- fixed (weights) region ----
  size_t off = 0;
  auto A_ = [&](size_t b){ size_t o = off; off = (off + b + 255) & ~(size_t)255; return o; };
  size_t oWT = A_((size_t)3*768*256*2);
  size_t oWO = A_((size_t)65536*2);
  size_t oW1 = A_((size_t)262144*2);
  size_t oW2 = A_((size_t)262144*2);
  size_t oBC = A_((size_t)2304*4);
  size_t oRW = A_(256);
  size_t fixedEnd = off;

  unsigned short* WT_CAT = (unsigned short*)(ws + oWT);
  unsigned short* WOUT_T = (unsigned short*)(ws + oWO);
  unsigned short* W1_T   = (unsigned short*)(ws + oW1);
  unsigned short* W2_T   = (unsigned short*)(ws + oW2);
  float*          BIASC  = (float*)(ws + oBC);
  float*          RW     = (float*)(ws + oRW);

  // ---- adaptive chunking over rows ----
  // per-row bytes: NBUF 3*256*2=1536 | RESID 256*4=1024 | QKV 3*768*2=4608
  const size_t PER_ROW = 7168;
  if (ws_size <= fixedEnd + 512) return;
  long maxR = (long)((ws_size - fixedEnd - 256) / PER_ROW);
  maxR &= ~127L;
  if (maxR < 128) return;
  long Rc = maxR < 16384 ? maxR : 16384;   // keep chunk working set L3-resident (117 MB)
  if (Rc > Brows) Rc = Brows;
  long nch = (Brows + Rc - 1) / Rc;
  Rc = ((Brows + nch - 1) / nch + 127) & ~127L;

  size_t chunkBase = (fixedEnd + 255) & ~(size_t)255;
  char* NB_B = ws + chunkBase;                              // 1536*Rc
  char* RS_B = NB_B + (size_t)1536*Rc;                      // 1024*Rc
  char* QK_B = RS_B + (size_t)1024*Rc;                      // 4608*Rc

  { // prep: weight transposes + bias concat + rw (also writes d_out tail)
    long total = 589824 + 65536 + 262144 + 262144 + 2304 + 3;
    int blocks = (int)((total + 255) / 256);
    k_prep<<<blocks, 256, 0, stream>>>(
        Wq24, Wk24, Wv24, Wq77, Wk77, Wv77, Wqx, Wkx, Wvx,
        bq24, bk24, bv24, bq77, bk77, bv77, bqx, bkx, bvx,
        Wout, W1, W2, radar_w,
        WT_CAT, WOUT_T, W1_T, W2_T, BIASC, RW, dout + (size_t)Brows*256);
  }

  for (long row0 = 0; row0 < Brows; row0 += Rc){
    long rows = Brows - row0 < Rc ? Brows - row0 : Rc;   // multiple of 128
    unsigned short* NBUF   = (unsigned short*)NB_B;
    float*          RESID  = (float*)RS_B;
    unsigned short* QKV    = (unsigned short*)QK_B;
    unsigned short* ATTN   = (unsigned short*)NB_B;      // alias (nbuf dead after gemm0)

    int tM = (int)(rows/128);

    k_ln3<<<(int)(rows/4), 256, 0, stream>>>(
        f24 + row0*256, f77 + row0*256, fx + row0*256,
        norm_g, norm_b, NBUF, RESID, (int)rows);

    { int tiles = tM*6*3; int grid = tiles < 512 ? tiles : 512;
      k_gemm256<0><<<grid, 256, 0, stream>>>(
          NBUF, WT_CAT, BIASC, QKV,
          rows*256L, 768L*256, 768L, rows*768L, 768, tM, 6, 3); }

    { int nTa = (int)(rows/8); int ga = nTa < 512 ? nTa : 512;
      k_attn<<<ga, 512, 0, stream>>>(QKV, RW, ATTN, (int)rows); }

    k_back<<<(int)(rows/32), 256, 0, stream>>>(
        ATTN, RESID, WOUT_T, W1_T, W2_T,
        bout, b1, b2, fnorm_g, fnorm_b, dout + row0*256);
  }
}